// Round 1
// baseline (393.801 us; speedup 1.0000x reference)
//
#include <hip/hip_runtime.h>
#include <hip/hip_bf16.h>
#include <stdint.h>

// Problem constants
#define NPIX   32768      // 32 * 32 * 32 flattened vectors
#define DIM    256        // embedding dim
#define KCODE  1024       // codebook entries
#define BSTRIDE 262144    // 256*32*32 floats per batch in NCHW
#define OUT0_N 8388608    // 32*256*32*32
// d_out layout: [0 .. 8388607] quantized_st, [8388608] loss, [8388609 ..] indices(float)

// ---------------------------------------------------------------------------
// numpy pairwise_sum replication (n=256 = pw128 + pw128), squares of elements.
// All roundings forced with __fmul_rn / __fadd_rn (no fma contraction).
// ---------------------------------------------------------------------------
__device__ __forceinline__ float pw128_sq(const float* __restrict__ p, int stride) {
    float r[8];
#pragma unroll
    for (int j = 0; j < 8; ++j) {
        float v = p[j * stride];
        r[j] = __fmul_rn(v, v);
    }
    for (int i = 8; i < 128; i += 8) {
#pragma unroll
        for (int j = 0; j < 8; ++j) {
            float v = p[(i + j) * stride];
            r[j] = __fadd_rn(r[j], __fmul_rn(v, v));
        }
    }
    float a = __fadd_rn(__fadd_rn(r[0], r[1]), __fadd_rn(r[2], r[3]));
    float b = __fadd_rn(__fadd_rn(r[4], r[5]), __fadd_rn(r[6], r[7]));
    return __fadd_rn(a, b);
}

__device__ __forceinline__ float pw256_sq(const float* __restrict__ p, int stride) {
    return __fadd_rn(pw128_sq(p, stride), pw128_sq(p + 128 * stride, stride));
}

// ---------------------------------------------------------------------------
// Kernel 1: s_x[n] = numpy-pairwise sum of x_n^2 (strided rows of NCHW input)
//           s_e[k] = numpy-pairwise sum of e_k^2 (contiguous rows)
//           also zeroes the loss accumulator.
// ---------------------------------------------------------------------------
__global__ void vq_sums(const float* __restrict__ in, const float* __restrict__ emb,
                        float* __restrict__ sx_arr, float* __restrict__ se_arr,
                        float* __restrict__ loss_acc) {
    int gid = blockIdx.x * 256 + threadIdx.x;
    if (gid == 0) *loss_acc = 0.0f;
    if (gid < NPIX) {
        int b = gid >> 10;
        int hw = gid & 1023;
        const float* p = in + (size_t)b * BSTRIDE + hw;   // stride 1024 over c
        sx_arr[gid] = pw256_sq(p, 1024);
    } else if (gid < NPIX + KCODE) {
        int k = gid - NPIX;
        se_arr[k] = pw256_sq(emb + (size_t)k * DIM, 1);
    }
}

// monotone float -> uint32 key (total order preserved for finite floats)
__device__ __forceinline__ unsigned int f2key(float f) {
    unsigned int u = __float_as_uint(f);
    return (u & 0x80000000u) ? ~u : (u | 0x80000000u);
}

// ---------------------------------------------------------------------------
// Kernel 2: split-K argmin GEMM.
// grid = 512: bx&255 -> n-tile of 128, bx>>8 -> k-half (512 codes each).
// block = 256 threads (tx = k dim 16, ty = n dim 16), 8x8 microtile.
// LDS-staged x[16d][128n], e[16d][128k(+4 pad)], fp32 fma accumulate.
// Per-candidate distance replicates numpy rounding:
//   d = round(round(sx - 2m) + se); ties -> smaller k via packed atomicMin.
// ---------------------------------------------------------------------------
__global__ __launch_bounds__(256, 2)
void vq_argmin(const float* __restrict__ in, const float* __restrict__ emb,
               const float* __restrict__ sx_arr, const float* __restrict__ se_arr,
               unsigned long long* __restrict__ ws64) {
    const int bx = blockIdx.x;
    const int nt = bx & 255;
    const int ks = bx >> 8;
    const int n0 = nt << 7;          // 128 n per tile
    const int b  = n0 >> 10;
    const int hw0 = n0 & 1023;
    const int tid = threadIdx.x;
    const int tx = tid & 15;
    const int ty = tid >> 4;

    __shared__ float xs[16][128];
    __shared__ float es[16][132];     // +4 pad: conflict-free transposed stores
    __shared__ float red_v[128][17];
    __shared__ int   red_k[128][17];

    float sx[8];
#pragma unroll
    for (int i = 0; i < 8; ++i) sx[i] = sx_arr[n0 + ty * 8 + i];

    float bmin[8];
    int   bidx[8];
#pragma unroll
    for (int i = 0; i < 8; ++i) { bmin[i] = __uint_as_float(0x7f800000u); bidx[i] = 0; }

    const float* xbase = in + (size_t)b * BSTRIDE + hw0;

    for (int kt = 0; kt < 4; ++kt) {
        const int k0 = ks * 512 + kt * 128;
        float se[8];
#pragma unroll
        for (int j = 0; j < 8; ++j) se[j] = se_arr[k0 + tx * 8 + j];

        float acc[8][8];
#pragma unroll
        for (int i = 0; i < 8; ++i)
#pragma unroll
            for (int j = 0; j < 8; ++j) acc[i][j] = 0.0f;

        for (int dc = 0; dc < 16; ++dc) {
            const int d0 = dc * 16;
            __syncthreads();   // previous-iteration readers done
            // stage x: 16 d x 128 n, coalesced along n
            {
                const int n4 = (tid & 31) * 4;
                const int dd = tid >> 5;
#pragma unroll
                for (int p = 0; p < 2; ++p) {
                    const int d = dd + 8 * p;
                    float4 v = *(const float4*)(xbase + (size_t)(d0 + d) * 1024 + n4);
                    *(float4*)&xs[d][n4] = v;
                }
            }
            // stage e (transposed): 128 k x 16 d
            {
                const int dq = (tid & 3) * 4;
                const int kb = tid >> 2;
#pragma unroll
                for (int p = 0; p < 2; ++p) {
                    const int k_l = kb + 64 * p;
                    float4 v = *(const float4*)(emb + (size_t)(k0 + k_l) * DIM + d0 + dq);
                    es[dq + 0][k_l] = v.x;
                    es[dq + 1][k_l] = v.y;
                    es[dq + 2][k_l] = v.z;
                    es[dq + 3][k_l] = v.w;
                }
            }
            __syncthreads();
#pragma unroll
            for (int d = 0; d < 16; ++d) {
                float4 a0 = *(const float4*)&xs[d][ty * 8];
                float4 a1 = *(const float4*)&xs[d][ty * 8 + 4];
                float4 b0 = *(const float4*)&es[d][tx * 8];
                float4 b1 = *(const float4*)&es[d][tx * 8 + 4];
                float av[8] = {a0.x, a0.y, a0.z, a0.w, a1.x, a1.y, a1.z, a1.w};
                float bv[8] = {b0.x, b0.y, b0.z, b0.w, b1.x, b1.y, b1.z, b1.w};
#pragma unroll
                for (int i = 0; i < 8; ++i)
#pragma unroll
                    for (int j = 0; j < 8; ++j)
                        acc[i][j] += av[i] * bv[j];
            }
        }
        // fold this k-tile into running per-thread argmin (numpy-faithful rounding)
#pragma unroll
        for (int i = 0; i < 8; ++i) {
#pragma unroll
            for (int j = 0; j < 8; ++j) {
                float t  = __fmaf_rn(-2.0f, acc[i][j], sx[i]);   // round(sx - 2m)
                float dv = __fadd_rn(t, se[j]);                  // round(+ se)
                int   k  = k0 + tx * 8 + j;
                if (dv < bmin[i]) { bmin[i] = dv; bidx[i] = k; }  // first-min (k ascending)
            }
        }
    }

    __syncthreads();
#pragma unroll
    for (int i = 0; i < 8; ++i) {
        red_v[ty * 8 + i][tx] = bmin[i];
        red_k[ty * 8 + i][tx] = bidx[i];
    }
    __syncthreads();
    if (tid < 128) {
        float bv = red_v[tid][0];
        int   bk = red_k[tid][0];
#pragma unroll
        for (int t = 1; t < 16; ++t) {
            float v = red_v[tid][t];
            int   kk = red_k[tid][t];
            if (v < bv || (v == bv && kk < bk)) { bv = v; bk = kk; }
        }
        unsigned long long packed = ((unsigned long long)f2key(bv) << 32) | (unsigned int)bk;
        atomicMin(&ws64[n0 + tid], packed);
    }
}

// ---------------------------------------------------------------------------
// Kernel 3: gather quantized rows, write straight-through output + indices,
// accumulate loss sum. grid = 256 blocks x 256 threads, 128 n per block.
// ---------------------------------------------------------------------------
__global__ void vq_write(const float* __restrict__ in, const float* __restrict__ emb,
                         const unsigned long long* __restrict__ ws64,
                         float* __restrict__ out0, float* __restrict__ out2,
                         float* __restrict__ loss_acc) {
    const int nt = blockIdx.x;
    const int n0 = nt << 7;
    const int b  = n0 >> 10;
    const int hw0 = n0 & 1023;
    const int tid = threadIdx.x;
    const int n_l = tid & 127;
    const int ch0 = tid >> 7;

    const int k = (int)(unsigned int)(ws64[n0 + n_l] & 0xFFFFFFFFull);
    if (tid < 128) out2[n0 + tid] = (float)k;

    const float* xrow = in  + (size_t)b * BSTRIDE + hw0 + n_l;
    float*       orow = out0 + (size_t)b * BSTRIDE + hw0 + n_l;
    const float* erow = emb + (size_t)k * DIM;

    float lsum = 0.0f;
    for (int it = 0; it < 128; ++it) {
        const int ch = it * 2 + ch0;
        float x = xrow[(size_t)ch * 1024];
        float q = erow[ch];
        float df = __fsub_rn(q, x);                 // round(q - x)
        orow[(size_t)ch * 1024] = __fadd_rn(x, df); // straight-through value
        lsum = __fadd_rn(lsum, __fmul_rn(df, df));
    }
    // block reduction: wave shuffle then LDS across 4 waves
#pragma unroll
    for (int off = 32; off >= 1; off >>= 1)
        lsum += __shfl_down(lsum, off, 64);
    __shared__ float wsum[4];
    if ((tid & 63) == 0) wsum[tid >> 6] = lsum;
    __syncthreads();
    if (tid == 0) {
        float t = wsum[0] + wsum[1] + wsum[2] + wsum[3];
        atomicAdd(loss_acc, t);
    }
}

// ---------------------------------------------------------------------------
// Kernel 4: finalize loss. mean = sum * 2^-23 (exact), loss = e + 0.25*e.
// ---------------------------------------------------------------------------
__global__ void vq_loss(const float* __restrict__ loss_acc, float* __restrict__ out1) {
    float s = *loss_acc;
    float e = s * (1.0f / 8388608.0f);      // division by 2^23, exact scaling
    out1[0] = __fadd_rn(e, __fmul_rn(0.25f, e));
}

extern "C" void kernel_launch(void* const* d_in, const int* in_sizes, int n_in,
                              void* d_out, int out_size, void* d_ws, size_t ws_size,
                              hipStream_t stream) {
    const float* in  = (const float*)d_in[0];
    const float* emb = (const float*)d_in[1];
    float* out = (float*)d_out;

    unsigned long long* ws64 = (unsigned long long*)d_ws;          // 32768 * 8 B
    float* wsf     = (float*)((char*)d_ws + NPIX * sizeof(unsigned long long));
    float* lossacc = wsf;                 // [0]
    float* sx_arr  = wsf + 256;           // 32768 floats
    float* se_arr  = wsf + 256 + NPIX;    // 1024 floats

    // init packed argmin slots to +inf key
    hipMemsetAsync(d_ws, 0xFF, NPIX * sizeof(unsigned long long), stream);

    vq_sums<<<(NPIX + KCODE + 255) / 256, 256, 0, stream>>>(in, emb, sx_arr, se_arr, lossacc);
    vq_argmin<<<512, 256, 0, stream>>>(in, emb, sx_arr, se_arr, ws64);
    vq_write<<<256, 256, 0, stream>>>(in, emb, ws64, out, out + OUT0_N + 1, lossacc);
    vq_loss<<<1, 1, 0, stream>>>(lossacc, out + OUT0_N);
}

// Round 2
// 386.158 us; speedup vs baseline: 1.0198x; 1.0198x over previous
//
#include <hip/hip_runtime.h>
#include <hip/hip_bf16.h>
#include <stdint.h>

// Problem constants
#define NPIX   32768      // 32 * 32 * 32 flattened vectors
#define DIM    256        // embedding dim
#define KCODE  1024       // codebook entries
#define BSTRIDE 262144    // 256*32*32 floats per batch in NCHW
#define OUT0_N 8388608    // 32*256*32*32
// d_out layout: [0 .. 8388607] quantized_st, [8388608] loss, [8388609 ..] indices(float)

// ---------------------------------------------------------------------------
// Kernel 1: parallel numpy-pairwise sums of squares.
// 16 threads per row. Thread j owns accumulator r[j&7] of pw128-half (j>>3):
//   r = v0*v0; r = r + v_i*v_i (15 sequential adds)  == pw128's r[jj] chain.
// Combine via commutative fadd butterflies (bitwise == ((r0+r1)+(r2+r3))+...,
// then low_half + high_half). Also inits ws64 slots and loss accumulator.
// ---------------------------------------------------------------------------
__global__ void vq_sums(const float* __restrict__ in, const float* __restrict__ emb,
                        float* __restrict__ sx_arr, float* __restrict__ se_arr,
                        float* __restrict__ loss_acc,
                        unsigned long long* __restrict__ ws64) {
    const int t = blockIdx.x * 256 + threadIdx.x;
    const int n = t >> 4;
    const int j = t & 15;
    if (t == 0) *loss_acc = 0.0f;

    const int dbase = (j >> 3) * 128 + (j & 7);
    float r;
    if (n < NPIX) {
        const int b = n >> 10;
        const int hw = n & 1023;
        const float* p = in + (size_t)b * BSTRIDE + hw;
        float v = p[(size_t)dbase * 1024];
        r = __fmul_rn(v, v);
#pragma unroll
        for (int i = 1; i < 16; ++i) {
            float u = p[(size_t)(dbase + i * 8) * 1024];
            r = __fadd_rn(r, __fmul_rn(u, u));
        }
    } else {
        const int k = n - NPIX;   // grid sized exactly: k < KCODE
        const float* p = emb + (size_t)k * DIM;
        float v = p[dbase];
        r = __fmul_rn(v, v);
#pragma unroll
        for (int i = 1; i < 16; ++i) {
            float u = p[dbase + i * 8];
            r = __fadd_rn(r, __fmul_rn(u, u));
        }
    }
    // exact pairwise tree (fp add is commutative bitwise):
    r = __fadd_rn(r, __shfl_xor(r, 1, 16));   // (r0+r1), (r2+r3), ...
    r = __fadd_rn(r, __shfl_xor(r, 2, 16));   // (r01+r23), (r45+r67)
    r = __fadd_rn(r, __shfl_xor(r, 4, 16));   // pw128 half-sum
    r = __fadd_rn(r, __shfl_xor(r, 8, 16));   // pw256 = low + high
    if (j == 0) {
        if (n < NPIX) {
            sx_arr[n] = r;
            ws64[n] = 0xFFFFFFFFFFFFFFFFull;
        } else {
            se_arr[n - NPIX] = r;
        }
    }
}

// monotone float -> uint32 key (total order preserved for finite floats)
__device__ __forceinline__ unsigned int f2key(float f) {
    unsigned int u = __float_as_uint(f);
    return (u & 0x80000000u) ? ~u : (u | 0x80000000u);
}

// ---------------------------------------------------------------------------
// Kernel 2: split-K=4 argmin GEMM.
// grid = 1024: bx&255 -> n-tile of 128 pixels, bx>>8 -> k-quarter (256 codes).
// block = 256 threads (tx = k dim 16, ty = n dim 16), 8x8 microtile.
// Thread tx owns k-locals {tx*4+c, 64+tx*4+c : c=0..3}  -> b-frag b128 reads
// stride 16 B/lane -> 2-way bank aliasing only (free).
// Accumulation: fp32 fmac over d = 0..255 ascending (bit-stable vs round 1).
// Fold: d = round(round(sx - 2m) + se); ties -> smaller k.
// Reduction over tx via width-16 shuffle butterfly; one atomicMin per pixel.
// ---------------------------------------------------------------------------
__global__ __launch_bounds__(256, 4)
void vq_argmin(const float* __restrict__ in, const float* __restrict__ emb,
               const float* __restrict__ sx_arr, const float* __restrict__ se_arr,
               unsigned long long* __restrict__ ws64) {
    const int bx = blockIdx.x;
    const int nt = bx & 255;
    const int ks = bx >> 8;
    const int n0 = nt << 7;          // 128 pixels per tile
    const int b  = n0 >> 10;
    const int hw0 = n0 & 1023;
    const int tid = threadIdx.x;
    const int tx = tid & 15;
    const int ty = tid >> 4;

    __shared__ float xs[16][128];
    __shared__ float es[16][132];     // +4 pad keeps transposed stores 2-way

    float bmin[8];
    int   bidx[8];
#pragma unroll
    for (int i = 0; i < 8; ++i) { bmin[i] = __uint_as_float(0x7f800000u); bidx[i] = 0; }

    const float* xbase = in + (size_t)b * BSTRIDE + hw0;

    for (int kt = 0; kt < 2; ++kt) {
        const int k0 = ks * 256 + kt * 128;

        float acc[8][8];
#pragma unroll
        for (int i = 0; i < 8; ++i)
#pragma unroll
            for (int j = 0; j < 8; ++j) acc[i][j] = 0.0f;

        for (int dc = 0; dc < 16; ++dc) {
            const int d0 = dc * 16;
            __syncthreads();   // previous-iteration readers done
            // stage x: 16 d x 128 n, coalesced along n
            {
                const int n4 = (tid & 31) * 4;
                const int dd = tid >> 5;
#pragma unroll
                for (int p = 0; p < 2; ++p) {
                    const int d = dd + 8 * p;
                    float4 v = *(const float4*)(xbase + (size_t)(d0 + d) * 1024 + n4);
                    *(float4*)&xs[d][n4] = v;
                }
            }
            // stage e (transposed): 128 k x 16 d
            {
                const int dq = (tid & 3) * 4;
                const int kb = tid >> 2;
#pragma unroll
                for (int p = 0; p < 2; ++p) {
                    const int k_l = kb + 64 * p;
                    float4 v = *(const float4*)(emb + (size_t)(k0 + k_l) * DIM + d0 + dq);
                    es[dq + 0][k_l] = v.x;
                    es[dq + 1][k_l] = v.y;
                    es[dq + 2][k_l] = v.z;
                    es[dq + 3][k_l] = v.w;
                }
            }
            __syncthreads();
#pragma unroll
            for (int d = 0; d < 16; ++d) {
                float4 a0 = *(const float4*)&xs[d][ty * 8];
                float4 a1 = *(const float4*)&xs[d][ty * 8 + 4];
                float4 b0 = *(const float4*)&es[d][tx * 4];        // k-locals tx*4..tx*4+3
                float4 b1 = *(const float4*)&es[d][tx * 4 + 64];   // k-locals 64+tx*4..+3
                float av[8] = {a0.x, a0.y, a0.z, a0.w, a1.x, a1.y, a1.z, a1.w};
                float bv[8] = {b0.x, b0.y, b0.z, b0.w, b1.x, b1.y, b1.z, b1.w};
#pragma unroll
                for (int i = 0; i < 8; ++i)
#pragma unroll
                    for (int j = 0; j < 8; ++j)
                        acc[i][j] += av[i] * bv[j];
            }
        }
        // fold this k-tile into running per-thread argmin (numpy-faithful rounding)
        float4 se0 = *(const float4*)(se_arr + k0 + tx * 4);
        float4 se1 = *(const float4*)(se_arr + k0 + 64 + tx * 4);
        float4 sx0 = *(const float4*)(sx_arr + n0 + ty * 8);
        float4 sx1 = *(const float4*)(sx_arr + n0 + ty * 8 + 4);
        float sxv[8] = {sx0.x, sx0.y, sx0.z, sx0.w, sx1.x, sx1.y, sx1.z, sx1.w};
        float sev[8] = {se0.x, se0.y, se0.z, se0.w, se1.x, se1.y, se1.z, se1.w};
#pragma unroll
        for (int i = 0; i < 8; ++i) {
#pragma unroll
            for (int j = 0; j < 8; ++j) {
                float t  = __fmaf_rn(-2.0f, acc[i][j], sxv[i]);  // round(sx - 2m)
                float dv = __fadd_rn(t, sev[j]);                 // round(+ se)
                int   k  = k0 + tx * 4 + (j & 3) + 64 * (j >> 2);
                if (dv < bmin[i]) { bmin[i] = dv; bidx[i] = k; } // j ascending == k ascending
            }
        }
    }

    // intra-wave reduction across tx (16 lanes per pixel-group), tie -> smaller k
#pragma unroll
    for (int i = 0; i < 8; ++i) {
        float v = bmin[i];
        int   k = bidx[i];
#pragma unroll
        for (int m = 1; m < 16; m <<= 1) {
            float ov = __shfl_xor(v, m, 16);
            int   ok = __shfl_xor(k, m, 16);
            if (ov < v || (ov == v && ok < k)) { v = ov; k = ok; }
        }
        if (tx == 0) {
            unsigned long long packed = ((unsigned long long)f2key(v) << 32) | (unsigned int)k;
            atomicMin(&ws64[n0 + ty * 8 + i], packed);
        }
    }
}

// ---------------------------------------------------------------------------
// Kernel 3: gather quantized rows, write straight-through output + indices,
// accumulate loss sum. grid = 256 blocks x 256 threads, 128 n per block.
// ---------------------------------------------------------------------------
__global__ void vq_write(const float* __restrict__ in, const float* __restrict__ emb,
                         const unsigned long long* __restrict__ ws64,
                         float* __restrict__ out0, float* __restrict__ out2,
                         float* __restrict__ loss_acc) {
    const int nt = blockIdx.x;
    const int n0 = nt << 7;
    const int b  = n0 >> 10;
    const int hw0 = n0 & 1023;
    const int tid = threadIdx.x;
    const int n_l = tid & 127;
    const int ch0 = tid >> 7;

    const int k = (int)(unsigned int)(ws64[n0 + n_l] & 0xFFFFFFFFull);
    if (tid < 128) out2[n0 + tid] = (float)k;

    const float* xrow = in  + (size_t)b * BSTRIDE + hw0 + n_l;
    float*       orow = out0 + (size_t)b * BSTRIDE + hw0 + n_l;
    const float* erow = emb + (size_t)k * DIM;

    float lsum = 0.0f;
    for (int it = 0; it < 128; ++it) {
        const int ch = it * 2 + ch0;
        float x = xrow[(size_t)ch * 1024];
        float q = erow[ch];
        float df = __fsub_rn(q, x);                 // round(q - x)
        orow[(size_t)ch * 1024] = __fadd_rn(x, df); // straight-through value
        lsum = __fadd_rn(lsum, __fmul_rn(df, df));
    }
    // block reduction: wave shuffle then LDS across 4 waves
#pragma unroll
    for (int off = 32; off >= 1; off >>= 1)
        lsum += __shfl_down(lsum, off, 64);
    __shared__ float wsum[4];
    if ((tid & 63) == 0) wsum[tid >> 6] = lsum;
    __syncthreads();
    if (tid == 0) {
        float t = wsum[0] + wsum[1] + wsum[2] + wsum[3];
        atomicAdd(loss_acc, t);
    }
}

// ---------------------------------------------------------------------------
// Kernel 4: finalize loss. mean = sum * 2^-23 (exact), loss = e + 0.25*e.
// ---------------------------------------------------------------------------
__global__ void vq_loss(const float* __restrict__ loss_acc, float* __restrict__ out1) {
    float s = *loss_acc;
    float e = s * (1.0f / 8388608.0f);      // division by 2^23, exact scaling
    out1[0] = __fadd_rn(e, __fmul_rn(0.25f, e));
}

extern "C" void kernel_launch(void* const* d_in, const int* in_sizes, int n_in,
                              void* d_out, int out_size, void* d_ws, size_t ws_size,
                              hipStream_t stream) {
    const float* in  = (const float*)d_in[0];
    const float* emb = (const float*)d_in[1];
    float* out = (float*)d_out;

    unsigned long long* ws64 = (unsigned long long*)d_ws;          // 32768 * 8 B
    float* wsf     = (float*)((char*)d_ws + NPIX * sizeof(unsigned long long));
    float* lossacc = wsf;                 // [0]
    float* sx_arr  = wsf + 256;           // 32768 floats
    float* se_arr  = wsf + 256 + NPIX;    // 1024 floats

    // vq_sums also inits ws64 (argmin slots) and the loss accumulator.
    vq_sums<<<(NPIX + KCODE) * 16 / 256, 256, 0, stream>>>(in, emb, sx_arr, se_arr, lossacc, ws64);
    vq_argmin<<<1024, 256, 0, stream>>>(in, emb, sx_arr, se_arr, ws64);
    vq_write<<<256, 256, 0, stream>>>(in, emb, ws64, out, out + OUT0_N + 1, lossacc);
    vq_loss<<<1, 1, 0, stream>>>(lossacc, out + OUT0_N);
}